// Round 3
// baseline (335.884 us; speedup 1.0000x reference)
//
#include <hip/hip_runtime.h>

// NGNNConv: out[i,j,:] = m[i,j] * [ (sum_{e: erow[e]=j} m[i,ecol[e]] * X[i,ecol[e],:]) @ W + b*cnt ]
// N=1024, E=8192, IND=OUTD=32, fp32.
//
// R5 design: cache-gather, high-ILP, barrier-free main loop.
//  - R4 post-mortem: 1 block/CU (148 KB LDS) + 5 barriers/round lockstepped 16
//    waves; 157 us with VALUBusy 22%, HBM 21%, occupancy 45% -> latency-bound.
//  - X[i] rows are gathered straight from L1/L2/L3 (all of X fits the 256 MB
//    L3; a row gather = 8 back-to-back dwordx4 = 2 full 64B lines, MSHR-merged).
//    LDS shrinks to ~27 KB -> 4 independent 256-thread blocks/CU, no main-loop
//    barriers, waves hide gather latency.
//  - Fold phase compacts ACTIVE sources per j (mask applied once per edge, not
//    per gather) and builds an ACTIVE-j worklist so the gather+matmul path runs
//    with full lanes; inactive j's get a cheap zero-store sweep.
//  - CSR via the proven tiny pre-kernel chain (R3: ~free vs in-block build).

#define NN   1024
#define IND  32
#define OUTD 32
#define EE   8192

typedef __attribute__((ext_vector_type(2))) float f32x2;

// ---------------- CSR build (parallel, 4 tiny kernels) ----------------
__global__ __launch_bounds__(1024) void k_zero(int* __restrict__ p, int n) {
    const int t = blockIdx.x * 1024 + threadIdx.x;
    if (t < n) p[t] = 0;
}

__global__ __launch_bounds__(1024) void k_count(const int* __restrict__ erow,
                                                int* __restrict__ cnt, int n_edges) {
    const int e = blockIdx.x * 1024 + threadIdx.x;
    if (e < n_edges) atomicAdd(&cnt[erow[e]], 1);
}

__global__ __launch_bounds__(1024) void k_scan(const int* __restrict__ cnt,
                                               int* __restrict__ row_ptr,
                                               int* __restrict__ fill) {
    __shared__ int sb[NN];
    const int t = threadIdx.x;
    const int v = cnt[t];
    sb[t] = v;
    __syncthreads();
    #pragma unroll
    for (int off = 1; off < NN; off <<= 1) {
        const int a = (t >= off) ? sb[t - off] : 0;
        __syncthreads();
        sb[t] += a;
        __syncthreads();
    }
    const int excl = sb[t] - v;
    row_ptr[t] = excl;
    fill[t]    = excl;
    if (t == NN - 1) row_ptr[NN] = sb[t];
}

__global__ __launch_bounds__(1024) void k_scatter(const int* __restrict__ erow,
                                                  const int* __restrict__ ecol,
                                                  int* __restrict__ fill,
                                                  int* __restrict__ cols, int n_edges) {
    const int e = blockIdx.x * 1024 + threadIdx.x;
    if (e < n_edges) {
        const int pos = atomicAdd(&fill[erow[e]], 1);
        cols[pos] = ecol[e];
    }
}

// ---------------- main: block per i, 256 threads, cache-gather ----------------
__global__ __launch_bounds__(256, 4) void ngnn_main_kernel(
    const float* __restrict__ X, const int* __restrict__ mask,
    const float* __restrict__ W, const float* __restrict__ b,
    const int* __restrict__ row_ptr, const int* __restrict__ cols,
    float* __restrict__ out)
{
    __shared__ float          maskf[NN];       // 4 KB
    __shared__ unsigned int   meta[NN];        // e0 | cnt<<16, active j only (4 KB)
    __shared__ unsigned short colsl[EE];       // compacted active sources (16 KB)
    __shared__ unsigned short alist[NN];       // active-j worklist (2 KB)
    __shared__ int            acount;

    const int t = threadIdx.x;
    const int i = blockIdx.x;

    if (t == 0) acount = 0;
    {   // mask row -> LDS (coalesced int4)
        const int4 m4 = ((const int4*)(mask + (size_t)i * NN))[t];
        maskf[4*t+0] = (float)m4.x; maskf[4*t+1] = (float)m4.y;
        maskf[4*t+2] = (float)m4.z; maskf[4*t+3] = (float)m4.w;
    }
    __syncthreads();

    // ---- Fold: compact active sources per active j; build active-j list ----
    #pragma unroll
    for (int p = 0; p < 4; ++p) {
        const int j = p * 256 + t;
        if (maskf[j] != 0.f) {
            const int a   = row_ptr[j];
            const int bnd = row_ptr[j + 1];
            int c = 0;
            for (int e = a; e < bnd; ++e) {
                const int k = cols[e] & (NN - 1);
                if (maskf[k] != 0.f) colsl[a + (c++)] = (unsigned short)k;
            }
            meta[j] = (unsigned)a | ((unsigned)c << 16);
            const int pos = atomicAdd(&acount, 1);   // wave-aggregated by compiler
            alist[pos] = (unsigned short)j;
        }
    }
    __syncthreads();

    // ---- Zero-store sweep for inactive j (fire-and-forget) ----
    const float4 z = {0.f, 0.f, 0.f, 0.f};
    #pragma unroll
    for (int p = 0; p < 4; ++p) {
        const int j = p * 256 + t;
        if (maskf[j] == 0.f) {
            float4* orow = (float4*)(out + ((size_t)i * NN + j) * OUTD);
            #pragma unroll
            for (int q = 0; q < 8; ++q) orow[q] = z;
        }
    }

    // ---- Process active j's (compacted -> full lanes on the hot path) ----
    const float4* Xi = (const float4*)(X + (size_t)i * NN * IND);
    const f32x2*  W2 = (const f32x2*)W;
    const f32x2*  b2 = (const f32x2*)b;
    const int na = acount;

    for (int a = t; a < na; a += 256) {
        const int j = (int)alist[a];
        const unsigned md = meta[j];
        const int e0 = (int)(md & 0xffffu);
        const int cn = (int)(md >> 16);

        float4 S4[8];
        #pragma unroll
        for (int s = 0; s < 8; ++s) S4[s] = z;

        for (int q = 0; q < cn; ++q) {
            const int k = (int)colsl[e0 + q];
            const float4* r = Xi + (k << 3);        // 128 B contiguous row
            #pragma unroll
            for (int s = 0; s < 8; ++s) {           // 8 dwordx4, MSHR-merged lines
                const float4 v = r[s];
                S4[s].x += v.x; S4[s].y += v.y; S4[s].z += v.z; S4[s].w += v.w;
            }
        }

        // o = S @ W + b*cnt   (W/b wave-uniform -> scalar loads)
        const float cf = (float)cn;
        f32x2 o2[16];
        #pragma unroll
        for (int c = 0; c < 16; ++c) o2[c] = b2[c] * cf;
        #pragma unroll
        for (int d = 0; d < IND; ++d) {
            const float sd = ((const float*)S4)[d];  // static after unroll
            #pragma unroll
            for (int c = 0; c < 16; ++c) o2[c] += W2[d * 16 + c] * sd;
        }

        float4* orow = (float4*)(out + ((size_t)i * NN + j) * OUTD);
        #pragma unroll
        for (int q2 = 0; q2 < 8; ++q2)
            orow[q2] = make_float4(o2[2*q2].x, o2[2*q2].y, o2[2*q2+1].x, o2[2*q2+1].y);
    }
}

extern "C" void kernel_launch(void* const* d_in, const int* in_sizes, int n_in,
                              void* d_out, int out_size, void* d_ws, size_t ws_size,
                              hipStream_t stream) {
    const float* X    = (const float*)d_in[0];
    const int*   mask = (const int*)d_in[1];
    const int*   erow = (const int*)d_in[2];
    const int*   ecol = (const int*)d_in[3];
    const float* W    = (const float*)d_in[4];
    const float* b    = (const float*)d_in[5];
    float*       out  = (float*)d_out;

    int n_edges = in_sizes[2];
    if (n_edges > EE) n_edges = EE;   // colsl capacity guard

    // ws layout (ints): cnt[1024] | row_ptr[1025] @1024 | fill[1024] @2560 | cols @4096
    int* cnt     = (int*)d_ws;
    int* row_ptr = cnt + 1024;
    int* fill    = cnt + 2560;
    int* cols    = cnt + 4096;

    const int eb = (n_edges + 1023) / 1024;
    k_zero   <<<1, 1024, 0, stream>>>(cnt, NN);
    k_count  <<<eb, 1024, 0, stream>>>(erow, cnt, n_edges);
    k_scan   <<<1, 1024, 0, stream>>>(cnt, row_ptr, fill);
    k_scatter<<<eb, 1024, 0, stream>>>(erow, ecol, fill, cols, n_edges);

    ngnn_main_kernel<<<NN, 256, 0, stream>>>(X, mask, W, b, row_ptr, cols, out);
}